// Round 1
// baseline (4375.200 us; speedup 1.0000x reference)
//
#include <hip/hip_runtime.h>
#include <math.h>

// Problem constants
#define NB 32          // batch
#define NC 1024        // channels
#define LTOT 680       // total tokens per batch
#define NTOK (NB*LTOT) // 21760
#define NKMAX 320      // 10 scales * 32 slots
#define NCHUNK 90      // 8-token chunks across all scales

// ---------------------------------------------------------------------------
// chunk -> (scale, l0, nq) lookup. Chunks never cross scale boundaries.
// scale sizes: 1,4,9,16,25,36,64,100,169,256 ; chunk counts: 1,1,2,2,4,5,8,13,22,32
// ---------------------------------------------------------------------------
__device__ __forceinline__ void chunk_info(int chunk, int* pi, int* pl0, int* pnq)
{
    const int cb[10] = {0,1,2,4,6,10,15,23,36,58};
    const int sb[10] = {0,1,5,14,30,55,91,155,255,424};
    const int se[10] = {1,5,14,30,55,91,155,255,424,680};
    int ii = 0;
#pragma unroll
    for (int k = 1; k < 10; ++k) if (chunk >= cb[k]) ii = k;
    int l0 = sb[ii] + (chunk - cb[ii]) * 8;
    int nq = se[ii] - l0; if (nq > 8) nq = 8;
    *pi = ii; *pl0 = l0; *pnq = nq;
}

// ---------------------------------------------------------------------------
// Generic fp32 tiled GEMM: C = scale * (A[MxK] @ B[KxN] + bias[N])
// 128x128 tile, BK=16, 256 threads, 8x8 per thread. M,N mult of 4; K mult of 16.
// scale = sigmoid(*scale_logit) if scale_logit != nullptr else 1.
// ---------------------------------------------------------------------------
__global__ __launch_bounds__(256) void gemm128(
    const float* __restrict__ A, const float* __restrict__ Bm,
    float* __restrict__ C, int M, int N, int K,
    const float* __restrict__ bias, const float* __restrict__ scale_logit)
{
    __shared__ float Ast[16][128];   // [k][m]
    __shared__ float Bs[16][128];    // [k][n]
    const int tid = threadIdx.x;
    const int m0 = blockIdx.x * 128;
    const int n0 = blockIdx.y * 128;
    const int tx = tid & 15;
    const int ty = tid >> 4;
    float acc[8][8];
#pragma unroll
    for (int i = 0; i < 8; ++i)
#pragma unroll
        for (int j = 0; j < 8; ++j) acc[i][j] = 0.f;

    const int lr = tid >> 2;          // A row within tile (0..63, +64)
    const int lk = (tid & 3) << 2;    // A k-quad
    const int br = tid >> 5;          // B k row (0..7, +8)
    const int bc = (tid & 31) << 2;   // B col quad

    for (int k0 = 0; k0 < K; k0 += 16) {
#pragma unroll
        for (int p = 0; p < 2; ++p) {
            int row = lr + (p << 6);
            int gm = m0 + row; if (gm > M - 1) gm = M - 1;   // clamp: garbage rows never stored
            const float4 a4 = *(const float4*)(A + (size_t)gm * K + k0 + lk);
            Ast[lk + 0][row] = a4.x;
            Ast[lk + 1][row] = a4.y;
            Ast[lk + 2][row] = a4.z;
            Ast[lk + 3][row] = a4.w;
        }
#pragma unroll
        for (int p = 0; p < 2; ++p) {
            int kr = br + (p << 3);
            int gn = n0 + bc; if (gn > N - 4) gn = N - 4;    // clamp: garbage cols never stored
            *(float4*)&Bs[kr][bc] = *(const float4*)(Bm + (size_t)(k0 + kr) * N + gn);
        }
        __syncthreads();
#pragma unroll
        for (int kk = 0; kk < 16; ++kk) {
            float a[8], b[8];
            *(float4*)&a[0] = *(float4*)&Ast[kk][(ty << 3)];
            *(float4*)&a[4] = *(float4*)&Ast[kk][(ty << 3) + 4];
            *(float4*)&b[0] = *(float4*)&Bs[kk][(tx << 3)];
            *(float4*)&b[4] = *(float4*)&Bs[kk][(tx << 3) + 4];
#pragma unroll
            for (int i = 0; i < 8; ++i)
#pragma unroll
                for (int j = 0; j < 8; ++j)
                    acc[i][j] = fmaf(a[i], b[j], acc[i][j]);
        }
        __syncthreads();
    }

    float scale = 1.0f;
    if (scale_logit) scale = 1.0f / (1.0f + expf(-scale_logit[0]));
#pragma unroll
    for (int i = 0; i < 8; ++i) {
        int gm = m0 + (ty << 3) + i;
        if (gm >= M) break;
#pragma unroll
        for (int jq = 0; jq < 2; ++jq) {
            int gn = n0 + (tx << 3) + (jq << 2);
            if (gn >= N) continue;
            float b0 = bias ? bias[gn + 0] : 0.f;
            float b1 = bias ? bias[gn + 1] : 0.f;
            float b2 = bias ? bias[gn + 2] : 0.f;
            float b3 = bias ? bias[gn + 3] : 0.f;
            float4 o;
            o.x = scale * (acc[i][(jq << 2) + 0] + b0);
            o.y = scale * (acc[i][(jq << 2) + 1] + b1);
            o.z = scale * (acc[i][(jq << 2) + 2] + b2);
            o.w = scale * (acc[i][(jq << 2) + 3] + b3);
            *(float4*)(C + (size_t)gm * N + gn) = o;
        }
    }
}

// ---------------------------------------------------------------------------
// 32x32 LDS-tiled transpose: out[Cc x R] = in[R x Cc]^T. R,Cc multiples of 32.
// ---------------------------------------------------------------------------
__global__ __launch_bounds__(256) void transpose32(
    const float* __restrict__ in, float* __restrict__ out, int R, int Cc)
{
    __shared__ float t[32][33];
    const int bx = blockIdx.x * 32;   // over Cc
    const int by = blockIdx.y * 32;   // over R
    const int x = threadIdx.x & 31;
    const int y0 = threadIdx.x >> 5;  // 0..7
#pragma unroll
    for (int yy = y0; yy < 32; yy += 8)
        t[yy][x] = in[(size_t)(by + yy) * Cc + bx + x];
    __syncthreads();
#pragma unroll
    for (int yy = y0; yy < 32; yy += 8)
        out[(size_t)(bx + yy) * R + by + x] = t[x][yy];
}

// ---------------------------------------------------------------------------
// kcT[b][c][j] = ksT[c][j] + sum_r a[b,v,r] * catBKT[c][(v*8+r)*32+slot]
// grid (NB, 1024), 320 threads (j = v*32+slot)
// ---------------------------------------------------------------------------
__global__ __launch_bounds__(320) void build_kcT(
    const float* __restrict__ ksT, const float* __restrict__ catBKT,
    const float* __restrict__ cat_A, const int* __restrict__ cat_ids,
    float* __restrict__ kcT)
{
    __shared__ float aS[80];
    const int b = blockIdx.x;
    const int c = blockIdx.y;
    const int tid = threadIdx.x;
    if (tid < 80) {
        int cid = cat_ids[b]; if (cid < 0) cid = 0;
        aS[tid] = cat_A[cid * 80 + tid];
    }
    __syncthreads();
    const int j = tid;
    const int v = j >> 5, slot = j & 31;
    float acc = ksT[(size_t)c * 320 + j];
    const float* row = catBKT + (size_t)c * 2560;
#pragma unroll
    for (int r = 0; r < 8; ++r)
        acc = fmaf(aS[v * 8 + r], row[(v * 8 + r) * 32 + slot], acc);
    kcT[((size_t)b * 1024 + c) * 320 + j] = acc;
}

// ---------------------------------------------------------------------------
// vc[b][j][c] = shared_v[j][c] + sum_r a[b,v,r] * cat_BV[(v,r,slot)][c]
// grid (NB, 320), 256 threads (c-quad per thread)
// ---------------------------------------------------------------------------
__global__ __launch_bounds__(256) void build_vc(
    const float* __restrict__ sv, const float* __restrict__ catBV,
    const float* __restrict__ cat_A, const int* __restrict__ cat_ids,
    float* __restrict__ vc)
{
    const int b = blockIdx.x;
    const int jrow = blockIdx.y;
    const int v = jrow >> 5, slot = jrow & 31;
    int cid = cat_ids[b]; if (cid < 0) cid = 0;
    float a[8];
#pragma unroll
    for (int r = 0; r < 8; ++r) a[r] = cat_A[(cid * 10 + v) * 8 + r];
    const int c = threadIdx.x << 2;
    float4 acc = *(const float4*)(sv + (size_t)jrow * 1024 + c);
#pragma unroll
    for (int r = 0; r < 8; ++r) {
        const float4 bv = *(const float4*)(catBV + (size_t)((v * 8 + r) * 32 + slot) * 1024 + c);
        acc.x = fmaf(a[r], bv.x, acc.x);
        acc.y = fmaf(a[r], bv.y, acc.y);
        acc.z = fmaf(a[r], bv.z, acc.z);
        acc.w = fmaf(a[r], bv.w, acc.w);
    }
    *(float4*)(vc + ((size_t)b * 320 + jrow) * 1024 + c) = acc;
}

// ---------------------------------------------------------------------------
// bias2[b][i][j] = ce[b]@aW1[1024:2048,j] + scale_emb[i]@aW1[2048:3072,j] + ab1[j]
// grid (NB*10), 128 threads
// ---------------------------------------------------------------------------
__global__ __launch_bounds__(128) void bias2_kernel(
    const float* __restrict__ cat_emb, const float* __restrict__ scale_emb,
    const float* __restrict__ aW1, const float* __restrict__ ab1,
    const int* __restrict__ cat_ids, float* __restrict__ bias2)
{
    const int b = blockIdx.x / 10;
    const int i = blockIdx.x - b * 10;
    const int j = threadIdx.x;
    int cid = cat_ids[b]; if (cid < 0) cid = 0;
    const float* ce = cat_emb + (size_t)cid * 1024;
    const float* se = scale_emb + (size_t)i * 1024;
    float acc = ab1[j];
    for (int c = 0; c < 1024; ++c) {
        acc = fmaf(ce[c], aW1[(size_t)(1024 + c) * 128 + j], acc);
        acc = fmaf(se[c], aW1[(size_t)(2048 + c) * 128 + j], acc);
    }
    bias2[(b * 10 + i) * 128 + j] = acc;
}

// ---------------------------------------------------------------------------
// alpha[b][l] = valid ? sigmoid( gelu(q@aW1_top + bias2[b,i]) @ aW2 + ab2 ) : 0
// one block per 8-token chunk, 128 threads (one hidden unit each)
// ---------------------------------------------------------------------------
__global__ __launch_bounds__(128) void alpha_kernel(
    const float* __restrict__ query, const float* __restrict__ aW1,
    const float* __restrict__ aW2, const float* __restrict__ ab2,
    const float* __restrict__ bias2, const int* __restrict__ cat_ids,
    float* __restrict__ alpha)
{
    __shared__ float qs[8][1024];
    __shared__ float red[8][128];
    const int tid = threadIdx.x;
    const int blk = blockIdx.x;
    const int b = blk / NCHUNK;
    const int chunk = blk - b * NCHUNK;
    int isc, l0, nq;
    chunk_info(chunk, &isc, &l0, &nq);
    const size_t qbase = ((size_t)b * LTOT + l0) * 1024;

    for (int idx = tid; idx < 8 * 256; idx += 128) {
        int t = idx >> 8;
        int c4 = (idx & 255) << 2;
        float4 v = make_float4(0.f, 0.f, 0.f, 0.f);
        if (t < nq) v = *(const float4*)(query + qbase + (size_t)t * 1024 + c4);
        *(float4*)&qs[t][c4] = v;
    }
    __syncthreads();
    const int j = tid;
    float acc[8];
#pragma unroll
    for (int t = 0; t < 8; ++t) acc[t] = 0.f;
    for (int c = 0; c < 1024; ++c) {
        float w = aW1[(size_t)c * 128 + j];
#pragma unroll
        for (int t = 0; t < 8; ++t) acc[t] = fmaf(qs[t][c], w, acc[t]);
    }
    const float b2 = bias2[(b * 10 + isc) * 128 + j];
    const float w2 = aW2[j];
#pragma unroll
    for (int t = 0; t < 8; ++t) {
        float h = acc[t] + b2;
        h = 0.5f * h * (1.0f + erff(h * 0.70710678118654752f));  // exact gelu
        red[t][j] = h * w2;
    }
    __syncthreads();
    if (tid < 8) {
        float s = 0.f;
        for (int jj = 0; jj < 128; ++jj) s += red[tid][jj];
        if (tid < nq) {
            float al = 0.f;
            if (cat_ids[b] >= 0) al = 1.f / (1.f + expf(-(s + ab2[0])));
            alpha[b * LTOT + l0 + tid] = al;
        }
    }
}

// ---------------------------------------------------------------------------
// Fused dual attention per 8-token chunk.
//  phase1: logits_s/logits_c via c-chunked LDS streaming of ksT/kcT
//  phase2: softmax, weighted by (1-alpha)/alpha
//  phase3: out = sum_j p_s*vs[j] + p_c*vc[b][j]
// LDS: kS 20KB + qsc 0.25KB + pS 25.6KB = ~46KB -> ~3 blocks/CU
// ---------------------------------------------------------------------------
__global__ __launch_bounds__(256) void attn_kernel(
    const float* __restrict__ query, const float* __restrict__ ksT,
    const float* __restrict__ kcT, const float* __restrict__ vs,
    const float* __restrict__ vc, const float* __restrict__ alpha,
    const float* __restrict__ log_temp, float* __restrict__ memo)
{
    __shared__ float kS[2][8][320];   // [type][c8][j]
    __shared__ float qsc[8][8];       // [t][c8]
    __shared__ float pS[320][20];     // [j][type*8+t], pad 20 for banks+alignment

    const int tid = threadIdx.x;
    const int blk = blockIdx.x;
    const int b = blk / NCHUNK;
    const int chunk = blk - b * NCHUNK;
    int isc, l0, nq;
    chunk_info(chunk, &isc, &l0, &nq);
    const int NK = (isc + 1) * 32;

    const float* kcTb = kcT + (size_t)b * 1024 * 320;
    const size_t qbase = ((size_t)b * LTOT + l0) * 1024;

    const int half = tid >> 7;        // 0,1 -> tokens 4h..4h+3
    const int lane128 = tid & 127;    // key lane; keys j = lane128 + 128u
    float accS[4][3], accC[4][3];
#pragma unroll
    for (int t = 0; t < 4; ++t)
#pragma unroll
        for (int u = 0; u < 3; ++u) { accS[t][u] = 0.f; accC[t][u] = 0.f; }

    for (int cc = 0; cc < 1024; cc += 8) {
        __syncthreads();
        for (int idx = tid; idx < 8 * NK; idx += 256) {
            int r = idx / NK;
            int j = idx - r * NK;
            kS[0][r][j] = ksT[(size_t)(cc + r) * 320 + j];
            kS[1][r][j] = kcTb[(size_t)(cc + r) * 320 + j];
        }
        if (tid < 64) {
            int t = tid >> 3, c8 = tid & 7;
            qsc[t][c8] = (t < nq) ? query[qbase + (size_t)t * 1024 + cc + c8] : 0.f;
        }
        __syncthreads();
#pragma unroll
        for (int c8 = 0; c8 < 8; ++c8) {
            float kv0[3], kv1[3];
#pragma unroll
            for (int u = 0; u < 3; ++u) {
                int j = lane128 + (u << 7);
                bool ok = j < NK;
                kv0[u] = ok ? kS[0][c8][j] : 0.f;
                kv1[u] = ok ? kS[1][c8][j] : 0.f;
            }
#pragma unroll
            for (int tt = 0; tt < 4; ++tt) {
                float qv = qsc[(half << 2) + tt][c8];
#pragma unroll
                for (int u = 0; u < 3; ++u) {
                    accS[tt][u] = fmaf(qv, kv0[u], accS[tt][u]);
                    accC[tt][u] = fmaf(qv, kv1[u], accC[tt][u]);
                }
            }
        }
    }
    __syncthreads();
#pragma unroll
    for (int u = 0; u < 3; ++u) {
        int j = lane128 + (u << 7);
        if (j < NK) {
#pragma unroll
            for (int tt = 0; tt < 4; ++tt) {
                pS[j][(half << 2) + tt] = accS[tt][u];
                pS[j][8 + (half << 2) + tt] = accC[tt][u];
            }
        }
    }
    __syncthreads();

    // phase2: softmax over j per (type, token) row; fold in alpha weighting
    {
        float temp = expf(log_temp[0]);
        temp = fminf(fmaxf(temp, 0.05f), 1.0f);
        const float Ksc = 0.03125f / temp;    // (1/sqrt(C)) / temp
        const int r = tid >> 4;               // 0..15 = type*8 + t
        const int s16 = tid & 15;
        const int type = r >> 3;
        const int t = r & 7;
        float mx = -1e30f;
        for (int j = s16; j < NK; j += 16) mx = fmaxf(mx, pS[j][r]);
#pragma unroll
        for (int k = 8; k >= 1; k >>= 1) mx = fmaxf(mx, __shfl_xor(mx, k, 64));
        float sum = 0.f;
        for (int j = s16; j < NK; j += 16) {
            float e = expf((pS[j][r] - mx) * Ksc);
            pS[j][r] = e;
            sum += e;
        }
#pragma unroll
        for (int k = 8; k >= 1; k >>= 1) sum += __shfl_xor(sum, k, 64);
        float al = (t < nq) ? alpha[b * LTOT + l0 + t] : 0.f;
        float wgt = (type == 0) ? (1.f - al) : al;
        float inv = wgt / sum;
        for (int j = s16; j < NK; j += 16) pS[j][r] *= inv;
    }
    __syncthreads();

    // phase3: each wave owns a 256-channel slab for all 8 tokens
    {
        const int w4 = tid >> 6;
        const int lane = tid & 63;
        const int cb = (w4 << 8) + (lane << 2);
        float4 acc[8];
#pragma unroll
        for (int t = 0; t < 8; ++t) acc[t] = make_float4(0.f, 0.f, 0.f, 0.f);
        const float* vcb = vc + (size_t)b * 320 * 1024;
        for (int j = 0; j < NK; ++j) {
            const float4 v0 = *(const float4*)(vs + (size_t)j * 1024 + cb);
            const float4 v1 = *(const float4*)(vcb + (size_t)j * 1024 + cb);
            float ps[8], pc[8];
            *(float4*)&ps[0] = *(const float4*)&pS[j][0];
            *(float4*)&ps[4] = *(const float4*)&pS[j][4];
            *(float4*)&pc[0] = *(const float4*)&pS[j][8];
            *(float4*)&pc[4] = *(const float4*)&pS[j][12];
#pragma unroll
            for (int t = 0; t < 8; ++t) {
                acc[t].x = fmaf(ps[t], v0.x, fmaf(pc[t], v1.x, acc[t].x));
                acc[t].y = fmaf(ps[t], v0.y, fmaf(pc[t], v1.y, acc[t].y));
                acc[t].z = fmaf(ps[t], v0.z, fmaf(pc[t], v1.z, acc[t].z));
                acc[t].w = fmaf(ps[t], v0.w, fmaf(pc[t], v1.w, acc[t].w));
            }
        }
#pragma unroll
        for (int t = 0; t < 8; ++t)
            if (t < nq)
                *(float4*)(memo + qbase + (size_t)t * 1024 + cb) = acc[t];
    }
}

__global__ void tail_zero(float* p)
{
    if (threadIdx.x < 2) p[threadIdx.x] = 0.f;
}

// ---------------------------------------------------------------------------
extern "C" void kernel_launch(void* const* d_in, const int* in_sizes, int n_in,
                              void* d_out, int out_size, void* d_ws, size_t ws_size,
                              hipStream_t stream)
{
    (void)in_sizes; (void)n_in;
    const float* x         = (const float*)d_in[0];
    const int*   cat_ids   = (const int*)  d_in[1];
    const float* sm        = (const float*)d_in[2];
    const float* cat_A     = (const float*)d_in[3];
    const float* cat_B     = (const float*)d_in[4];
    const float* cat_emb   = (const float*)d_in[5];
    const float* scale_emb = (const float*)d_in[6];
    const float* Wq        = (const float*)d_in[7];
    const float* Wk        = (const float*)d_in[8];
    const float* Wv        = (const float*)d_in[9];
    const float* aW1       = (const float*)d_in[10];
    const float* ab1       = (const float*)d_in[11];
    const float* aW2       = (const float*)d_in[12];
    const float* ab2       = (const float*)d_in[13];
    const float* kW1       = (const float*)d_in[14];
    const float* kb1       = (const float*)d_in[15];
    const float* kW2       = (const float*)d_in[16];
    const float* kb2       = (const float*)d_in[17];
    const float* vW1       = (const float*)d_in[18];
    const float* vb1       = (const float*)d_in[19];
    const float* vW2       = (const float*)d_in[20];
    const float* vb2       = (const float*)d_in[21];
    const float* gk        = (const float*)d_in[22];
    const float* gv        = (const float*)d_in[23];
    const float* log_temp  = (const float*)d_in[24];

    float* out   = (float*)d_out;
    float* memb  = out;                        // mem, later overwritten by mem_k
    float* query = out + (size_t)NTOK * NC;    // query, later overwritten by mem_v

    // workspace layout (floats)
    float* w     = (float*)d_ws;
    float* sk    = w;                  // 327680
    float* sv    = sk    + 327680;     // 327680
    float* ksT   = sv    + 327680;     // 327680
    float* kcT   = ksT   + 327680;     // 10485760
    float* vc    = kcT   + 10485760;   // 10485760
    float* alph  = vc    + 10485760;   // 21760
    float* bias2 = alph  + 21760;      // 40960
    float* bufA  = bias2 + 40960;      // 2621440  (cat_BK, later t1k)
    float* bufB  = bufA  + 2621440;    // 2621440  (cat_BV, later t1v)
    float* bufC  = bufB  + 2621440;    // 2621440  (cat_BK transposed)
    if (ws_size < (size_t)29881600 * 4) return;
    if (out_size < 2 * NTOK * NC + 2) return;

    const dim3 blk256(256);

    // projections (batch-independent)
    gemm128<<<dim3(170, 8), blk256, 0, stream>>>(x, Wq, query, NTOK, NC, NC, nullptr, nullptr);
    gemm128<<<dim3(3, 8),   blk256, 0, stream>>>(sm, Wk, sk, 320, NC, NC, nullptr, nullptr);
    gemm128<<<dim3(3, 8),   blk256, 0, stream>>>(sm, Wv, sv, 320, NC, NC, nullptr, nullptr);
    gemm128<<<dim3(20, 8),  blk256, 0, stream>>>(cat_B, Wk, bufA, 2560, NC, NC, nullptr, nullptr);
    gemm128<<<dim3(20, 8),  blk256, 0, stream>>>(cat_B, Wv, bufB, 2560, NC, NC, nullptr, nullptr);

    // transposed key layouts for coalesced logits streaming
    transpose32<<<dim3(32, 10), blk256, 0, stream>>>(sk,   ksT,  320,  1024);
    transpose32<<<dim3(32, 80), blk256, 0, stream>>>(bufA, bufC, 2560, 1024);

    // per-batch low-rank expanded K/V memories
    build_kcT<<<dim3(NB, 1024), dim3(320), 0, stream>>>(ksT, bufC, cat_A, cat_ids, kcT);
    build_vc<<<dim3(NB, 320), blk256, 0, stream>>>(sv, bufB, cat_A, cat_ids, vc);

    // alpha gate
    bias2_kernel<<<dim3(NB * 10), dim3(128), 0, stream>>>(cat_emb, scale_emb, aW1, ab1, cat_ids, bias2);
    alpha_kernel<<<dim3(NB * NCHUNK), dim3(128), 0, stream>>>(query, aW1, aW2, ab2, bias2, cat_ids, alph);

    // fused dual attention -> mem (in d_out)
    attn_kernel<<<dim3(NB * NCHUNK), blk256, 0, stream>>>(query, ksT, kcT, sv, vc, alph, log_temp, memb);

    // final low-rank projections
    gemm128<<<dim3(170, 1), blk256, 0, stream>>>(memb, kW1, bufA, NTOK, 64, NC, kb1, nullptr);
    gemm128<<<dim3(170, 1), blk256, 0, stream>>>(memb, vW1, bufB, NTOK, 64, NC, vb1, nullptr);
    gemm128<<<dim3(170, 8), blk256, 0, stream>>>(bufA, kW2, memb, NTOK, NC, 64, kb2, gk);   // mem_k over mem
    gemm128<<<dim3(170, 8), blk256, 0, stream>>>(bufB, vW2, query, NTOK, NC, 64, vb2, gv);  // mem_v over query

    tail_zero<<<1, 64, 0, stream>>>(out + (size_t)2 * NTOK * NC);
}

// Round 2
// 3200.523 us; speedup vs baseline: 1.3670x; 1.3670x over previous
//
#include <hip/hip_runtime.h>
#include <math.h>

// Problem constants
#define NB 32          // batch
#define NC 1024        // channels
#define LTOT 680       // total tokens per batch
#define NTOK (NB*LTOT) // 21760
#define NKMAX 320      // 10 scales * 32 slots
#define NCHUNK 90      // 8-token chunks across all scales (alpha kernel)
#define NTILE 27       // 32-token tiles across all scales (attn kernel)

// ---------------------------------------------------------------------------
// chunk -> (scale, l0, nq) lookup for alpha kernel (8-token chunks).
// ---------------------------------------------------------------------------
__device__ __forceinline__ void chunk_info(int chunk, int* pi, int* pl0, int* pnq)
{
    const int cb[10] = {0,1,2,4,6,10,15,23,36,58};
    const int sb[10] = {0,1,5,14,30,55,91,155,255,424};
    const int se[10] = {1,5,14,30,55,91,155,255,424,680};
    int ii = 0;
#pragma unroll
    for (int k = 1; k < 10; ++k) if (chunk >= cb[k]) ii = k;
    int l0 = sb[ii] + (chunk - cb[ii]) * 8;
    int nq = se[ii] - l0; if (nq > 8) nq = 8;
    *pi = ii; *pl0 = l0; *pnq = nq;
}

// 32-token attention tiles, heavy-first (scale 9 first) for tail balance.
__device__ __constant__ int d_tscale[NTILE] =
    {9,9,9,9,9,9,9,9, 8,8,8,8,8,8, 7,7,7,7, 6,6, 5,5, 4,3,2,1,0};
__device__ __constant__ int d_tl0[NTILE] =
    {424,456,488,520,552,584,616,648, 255,287,319,351,383,415,
     155,187,219,251, 91,123, 55,87, 30,14,5,1,0};
__device__ __constant__ int d_tnt[NTILE] =
    {32,32,32,32,32,32,32,32, 32,32,32,32,32,9, 32,32,32,4, 32,32, 32,4, 25,16,9,4,1};

// ---------------------------------------------------------------------------
// Generic fp32 tiled GEMM: C = scale * (A[MxK] @ B[KxN] + bias[N])
// ---------------------------------------------------------------------------
__global__ __launch_bounds__(256) void gemm128(
    const float* __restrict__ A, const float* __restrict__ Bm,
    float* __restrict__ C, int M, int N, int K,
    const float* __restrict__ bias, const float* __restrict__ scale_logit)
{
    __shared__ float Ast[16][128];   // [k][m]
    __shared__ float Bs[16][128];    // [k][n]
    const int tid = threadIdx.x;
    const int m0 = blockIdx.x * 128;
    const int n0 = blockIdx.y * 128;
    const int tx = tid & 15;
    const int ty = tid >> 4;
    float acc[8][8];
#pragma unroll
    for (int i = 0; i < 8; ++i)
#pragma unroll
        for (int j = 0; j < 8; ++j) acc[i][j] = 0.f;

    const int lr = tid >> 2;
    const int lk = (tid & 3) << 2;
    const int br = tid >> 5;
    const int bc = (tid & 31) << 2;

    for (int k0 = 0; k0 < K; k0 += 16) {
#pragma unroll
        for (int p = 0; p < 2; ++p) {
            int row = lr + (p << 6);
            int gm = m0 + row; if (gm > M - 1) gm = M - 1;
            const float4 a4 = *(const float4*)(A + (size_t)gm * K + k0 + lk);
            Ast[lk + 0][row] = a4.x;
            Ast[lk + 1][row] = a4.y;
            Ast[lk + 2][row] = a4.z;
            Ast[lk + 3][row] = a4.w;
        }
#pragma unroll
        for (int p = 0; p < 2; ++p) {
            int kr = br + (p << 3);
            int gn = n0 + bc; if (gn > N - 4) gn = N - 4;
            *(float4*)&Bs[kr][bc] = *(const float4*)(Bm + (size_t)(k0 + kr) * N + gn);
        }
        __syncthreads();
#pragma unroll
        for (int kk = 0; kk < 16; ++kk) {
            float a[8], b[8];
            *(float4*)&a[0] = *(float4*)&Ast[kk][(ty << 3)];
            *(float4*)&a[4] = *(float4*)&Ast[kk][(ty << 3) + 4];
            *(float4*)&b[0] = *(float4*)&Bs[kk][(tx << 3)];
            *(float4*)&b[4] = *(float4*)&Bs[kk][(tx << 3) + 4];
#pragma unroll
            for (int i = 0; i < 8; ++i)
#pragma unroll
                for (int j = 0; j < 8; ++j)
                    acc[i][j] = fmaf(a[i], b[j], acc[i][j]);
        }
        __syncthreads();
    }

    float scale = 1.0f;
    if (scale_logit) scale = 1.0f / (1.0f + expf(-scale_logit[0]));
#pragma unroll
    for (int i = 0; i < 8; ++i) {
        int gm = m0 + (ty << 3) + i;
        if (gm >= M) break;
#pragma unroll
        for (int jq = 0; jq < 2; ++jq) {
            int gn = n0 + (tx << 3) + (jq << 2);
            if (gn >= N) continue;
            float b0 = bias ? bias[gn + 0] : 0.f;
            float b1 = bias ? bias[gn + 1] : 0.f;
            float b2 = bias ? bias[gn + 2] : 0.f;
            float b3 = bias ? bias[gn + 3] : 0.f;
            float4 o;
            o.x = scale * (acc[i][(jq << 2) + 0] + b0);
            o.y = scale * (acc[i][(jq << 2) + 1] + b1);
            o.z = scale * (acc[i][(jq << 2) + 2] + b2);
            o.w = scale * (acc[i][(jq << 2) + 3] + b3);
            *(float4*)(C + (size_t)gm * N + gn) = o;
        }
    }
}

// ---------------------------------------------------------------------------
// 32x32 LDS-tiled transpose
// ---------------------------------------------------------------------------
__global__ __launch_bounds__(256) void transpose32(
    const float* __restrict__ in, float* __restrict__ out, int R, int Cc)
{
    __shared__ float t[32][33];
    const int bx = blockIdx.x * 32;
    const int by = blockIdx.y * 32;
    const int x = threadIdx.x & 31;
    const int y0 = threadIdx.x >> 5;
#pragma unroll
    for (int yy = y0; yy < 32; yy += 8)
        t[yy][x] = in[(size_t)(by + yy) * Cc + bx + x];
    __syncthreads();
#pragma unroll
    for (int yy = y0; yy < 32; yy += 8)
        out[(size_t)(bx + yy) * R + by + x] = t[x][yy];
}

// ---------------------------------------------------------------------------
// kcT[b][c][j] = ksT[c][j] + sum_r a[b,v,r] * catBKT[c][(v*8+r)*32+slot]
// ---------------------------------------------------------------------------
__global__ __launch_bounds__(320) void build_kcT(
    const float* __restrict__ ksT, const float* __restrict__ catBKT,
    const float* __restrict__ cat_A, const int* __restrict__ cat_ids,
    float* __restrict__ kcT)
{
    __shared__ float aS[80];
    const int b = blockIdx.x;
    const int c = blockIdx.y;
    const int tid = threadIdx.x;
    if (tid < 80) {
        int cid = cat_ids[b]; if (cid < 0) cid = 0;
        aS[tid] = cat_A[cid * 80 + tid];
    }
    __syncthreads();
    const int j = tid;
    const int v = j >> 5, slot = j & 31;
    float acc = ksT[(size_t)c * 320 + j];
    const float* row = catBKT + (size_t)c * 2560;
#pragma unroll
    for (int r = 0; r < 8; ++r)
        acc = fmaf(aS[v * 8 + r], row[(v * 8 + r) * 32 + slot], acc);
    kcT[((size_t)b * 1024 + c) * 320 + j] = acc;
}

// ---------------------------------------------------------------------------
// vc[b][j][c] = shared_v[j][c] + sum_r a[b,v,r] * cat_BV[(v,r,slot)][c]
// ---------------------------------------------------------------------------
__global__ __launch_bounds__(256) void build_vc(
    const float* __restrict__ sv, const float* __restrict__ catBV,
    const float* __restrict__ cat_A, const int* __restrict__ cat_ids,
    float* __restrict__ vc)
{
    const int b = blockIdx.x;
    const int jrow = blockIdx.y;
    const int v = jrow >> 5, slot = jrow & 31;
    int cid = cat_ids[b]; if (cid < 0) cid = 0;
    float a[8];
#pragma unroll
    for (int r = 0; r < 8; ++r) a[r] = cat_A[(cid * 10 + v) * 8 + r];
    const int c = threadIdx.x << 2;
    float4 acc = *(const float4*)(sv + (size_t)jrow * 1024 + c);
#pragma unroll
    for (int r = 0; r < 8; ++r) {
        const float4 bv = *(const float4*)(catBV + (size_t)((v * 8 + r) * 32 + slot) * 1024 + c);
        acc.x = fmaf(a[r], bv.x, acc.x);
        acc.y = fmaf(a[r], bv.y, acc.y);
        acc.z = fmaf(a[r], bv.z, acc.z);
        acc.w = fmaf(a[r], bv.w, acc.w);
    }
    *(float4*)(vc + ((size_t)b * 320 + jrow) * 1024 + c) = acc;
}

// ---------------------------------------------------------------------------
// bias2[b][i][j] = ce[b]@aW1[1024:2048,j] + scale_emb[i]@aW1[2048:3072,j] + ab1[j]
// ---------------------------------------------------------------------------
__global__ __launch_bounds__(128) void bias2_kernel(
    const float* __restrict__ cat_emb, const float* __restrict__ scale_emb,
    const float* __restrict__ aW1, const float* __restrict__ ab1,
    const int* __restrict__ cat_ids, float* __restrict__ bias2)
{
    const int b = blockIdx.x / 10;
    const int i = blockIdx.x - b * 10;
    const int j = threadIdx.x;
    int cid = cat_ids[b]; if (cid < 0) cid = 0;
    const float* ce = cat_emb + (size_t)cid * 1024;
    const float* se = scale_emb + (size_t)i * 1024;
    float acc = ab1[j];
    for (int c = 0; c < 1024; ++c) {
        acc = fmaf(ce[c], aW1[(size_t)(1024 + c) * 128 + j], acc);
        acc = fmaf(se[c], aW1[(size_t)(2048 + c) * 128 + j], acc);
    }
    bias2[(b * 10 + i) * 128 + j] = acc;
}

// ---------------------------------------------------------------------------
// alpha[b][l] = valid ? sigmoid( gelu(q@aW1_top + bias2[b,i]) @ aW2 + ab2 ) : 0
// ---------------------------------------------------------------------------
__global__ __launch_bounds__(128) void alpha_kernel(
    const float* __restrict__ query, const float* __restrict__ aW1,
    const float* __restrict__ aW2, const float* __restrict__ ab2,
    const float* __restrict__ bias2, const int* __restrict__ cat_ids,
    float* __restrict__ alpha)
{
    __shared__ float qs[8][1024];
    __shared__ float red[8][128];
    const int tid = threadIdx.x;
    const int blk = blockIdx.x;
    const int b = blk / NCHUNK;
    const int chunk = blk - b * NCHUNK;
    int isc, l0, nq;
    chunk_info(chunk, &isc, &l0, &nq);
    const size_t qbase = ((size_t)b * LTOT + l0) * 1024;

    for (int idx = tid; idx < 8 * 256; idx += 128) {
        int t = idx >> 8;
        int c4 = (idx & 255) << 2;
        float4 v = make_float4(0.f, 0.f, 0.f, 0.f);
        if (t < nq) v = *(const float4*)(query + qbase + (size_t)t * 1024 + c4);
        *(float4*)&qs[t][c4] = v;
    }
    __syncthreads();
    const int j = tid;
    float acc[8];
#pragma unroll
    for (int t = 0; t < 8; ++t) acc[t] = 0.f;
    for (int c = 0; c < 1024; ++c) {
        float w = aW1[(size_t)c * 128 + j];
#pragma unroll
        for (int t = 0; t < 8; ++t) acc[t] = fmaf(qs[t][c], w, acc[t]);
    }
    const float b2 = bias2[(b * 10 + isc) * 128 + j];
    const float w2 = aW2[j];
#pragma unroll
    for (int t = 0; t < 8; ++t) {
        float h = acc[t] + b2;
        h = 0.5f * h * (1.0f + erff(h * 0.70710678118654752f));
        red[t][j] = h * w2;
    }
    __syncthreads();
    if (tid < 8) {
        float s = 0.f;
        for (int jj = 0; jj < 128; ++jj) s += red[tid][jj];
        if (tid < nq) {
            float al = 0.f;
            if (cat_ids[b] >= 0) al = 1.f / (1.f + expf(-(s + ab2[0])));
            alpha[b * LTOT + l0 + tid] = al;
        }
    }
}

// ---------------------------------------------------------------------------
// Fused dual attention v2: 32-token tiles, per-type sequential passes.
//  Pass S: logits(Q,ksT) -> softmax*(1-alpha) -> +=P@Vs -> store memo
//  Pass C: logits(Q,kcT[b]) -> softmax*alpha  -> memo += P@Vc
// LDS: kS 10.2KB + Qs 1.2KB + pS 40KB = 52.3KB -> 3 blocks/CU (12 waves).
// Thread org: 4 waves = 4 token-groups of 8; lane owns keys j=lane+64u.
// ---------------------------------------------------------------------------
__global__ __launch_bounds__(256) void attn_kernel2(
    const float* __restrict__ query, const float* __restrict__ ksT,
    const float* __restrict__ kcT, const float* __restrict__ vs,
    const float* __restrict__ vc, const float* __restrict__ alpha,
    const float* __restrict__ log_temp, float* __restrict__ memo)
{
    __shared__ float kS[8][320];   // [c8][j] one type at a time
    __shared__ float Qs[8][36];    // [c8][tok] (pad 36: 16B-aligned b128 reads)
    __shared__ float pS[32][320];  // [tok][j]

    const int tid = threadIdx.x;
    const int tile = blockIdx.x >> 5;
    const int b    = blockIdx.x & 31;

    const int isc  = d_tscale[tile];
    const int l0   = d_tl0[tile];
    const int ntok = d_tnt[tile];
    const int NK   = (isc + 1) << 5;
    const int NK4  = NK >> 2;
    const int NKu  = (NK + 63) >> 6;   // key-groups of 64 per lane (<=5)

    const int lane = tid & 63;
    const int tg   = tid >> 6;         // wave id = token group
    const int tg8  = tg << 3;

    const size_t qbase = ((size_t)b * LTOT + l0) * 1024;

    float temp = __expf(log_temp[0]);
    temp = fminf(fmaxf(temp, 0.05f), 1.0f);
    const float Ksc = 0.03125f / temp;

    const int sr = tid >> 5;           // staging row 0..7
    const int sc = tid & 31;           // staging f4 lane

    for (int type = 0; type < 2; ++type) {
        const float* kT = type ? (kcT + (size_t)b * 1024 * 320) : ksT;
        const float* V  = type ? (vc  + (size_t)b * 320 * 1024) : vs;

        // ---------- phase 1: logits ----------
        float acc[8][5];
#pragma unroll
        for (int t = 0; t < 8; ++t)
#pragma unroll
            for (int u = 0; u < 5; ++u) acc[t][u] = 0.f;

        for (int cc = 0; cc < 1024; cc += 8) {
            __syncthreads();
            // stage K rows [8][NK] (each f4 loaded once, no division)
            {
                const float4* src4 = (const float4*)(kT + (size_t)(cc + sr) * 320);
                float4* dst4 = (float4*)&kS[sr][0];
                for (int k = sc; k < NK4; k += 32) dst4[k] = src4[k];
            }
            // stage Q chunk transposed [c8][tok]
            {
                int c8 = tid >> 5, t = tid & 31;
                Qs[c8][t] = (t < ntok) ? query[qbase + (size_t)t * 1024 + cc + c8] : 0.f;
            }
            __syncthreads();
#pragma unroll
            for (int c8 = 0; c8 < 8; ++c8) {
                float qv[8];
                *(float4*)&qv[0] = *(float4*)&Qs[c8][tg8];
                *(float4*)&qv[4] = *(float4*)&Qs[c8][tg8 + 4];
#pragma unroll
                for (int u = 0; u < 5; ++u) {
                    if (u >= NKu) break;
                    int j = lane + (u << 6);
                    float kv = (j < NK) ? kS[c8][j] : 0.f;
#pragma unroll
                    for (int t = 0; t < 8; ++t)
                        acc[t][u] = fmaf(qv[t], kv, acc[t][u]);
                }
            }
        }
        // write logits to pS[tok][j] (lane-consecutive j: conflict-free)
#pragma unroll
        for (int u = 0; u < 5; ++u) {
            if (u >= NKu) break;
            int j = lane + (u << 6);
            if (j < NK) {
#pragma unroll
                for (int t = 0; t < 8; ++t) pS[tg8 + t][j] = acc[t][u];
            }
        }
        __syncthreads();

        // ---------- phase 2: softmax + alpha weighting ----------
        {
            const int tok = tid >> 3;
            const int sj  = tid & 7;
            float mx = -1e30f;
            for (int j = sj; j < NK; j += 8) mx = fmaxf(mx, pS[tok][j]);
#pragma unroll
            for (int k = 4; k >= 1; k >>= 1) mx = fmaxf(mx, __shfl_xor(mx, k, 8));
            float sum = 0.f;
            for (int j = sj; j < NK; j += 8) {
                float e = __expf((pS[tok][j] - mx) * Ksc);
                pS[tok][j] = e;
                sum += e;
            }
#pragma unroll
            for (int k = 4; k >= 1; k >>= 1) sum += __shfl_xor(sum, k, 8);
            float al = (tok < ntok) ? alpha[b * LTOT + l0 + tok] : 0.f;
            float wgt = type ? al : (1.f - al);
            float inv = wgt / sum;
            for (int j = sj; j < NK; j += 8) pS[tok][j] *= inv;
        }
        __syncthreads();

        // ---------- phase 3: O += P @ V ----------
        {
            const int nvalid = ntok - tg8;
#pragma unroll 1
            for (int slab = 0; slab < 4; ++slab) {
                float4 a3[8];
#pragma unroll
                for (int t = 0; t < 8; ++t) a3[t] = make_float4(0.f, 0.f, 0.f, 0.f);
                const float* Vb = V + (slab << 8) + (lane << 2);
#pragma unroll 4
                for (int j = 0; j < NK; ++j) {
                    const float4 v4 = *(const float4*)(Vb + (size_t)j * 1024);
                    float p[8];
#pragma unroll
                    for (int t = 0; t < 8; ++t) p[t] = pS[tg8 + t][j];
#pragma unroll
                    for (int t = 0; t < 8; ++t) {
                        a3[t].x = fmaf(p[t], v4.x, a3[t].x);
                        a3[t].y = fmaf(p[t], v4.y, a3[t].y);
                        a3[t].z = fmaf(p[t], v4.z, a3[t].z);
                        a3[t].w = fmaf(p[t], v4.w, a3[t].w);
                    }
                }
#pragma unroll
                for (int t = 0; t < 8; ++t) {
                    if (t < nvalid) {
                        float* op = memo + qbase + (size_t)(tg8 + t) * 1024
                                    + (slab << 8) + (lane << 2);
                        if (type == 0) {
                            *(float4*)op = a3[t];
                        } else {
                            float4 o = *(const float4*)op;
                            o.x += a3[t].x; o.y += a3[t].y;
                            o.z += a3[t].z; o.w += a3[t].w;
                            *(float4*)op = o;
                        }
                    }
                }
            }
        }
        __syncthreads();   // protect pS/kS before next type pass
    }
}

__global__ void tail_zero(float* p)
{
    if (threadIdx.x < 2) p[threadIdx.x] = 0.f;
}

// ---------------------------------------------------------------------------
extern "C" void kernel_launch(void* const* d_in, const int* in_sizes, int n_in,
                              void* d_out, int out_size, void* d_ws, size_t ws_size,
                              hipStream_t stream)
{
    (void)in_sizes; (void)n_in;
    const float* x         = (const float*)d_in[0];
    const int*   cat_ids   = (const int*)  d_in[1];
    const float* sm        = (const float*)d_in[2];
    const float* cat_A     = (const float*)d_in[3];
    const float* cat_B     = (const float*)d_in[4];
    const float* cat_emb   = (const float*)d_in[5];
    const float* scale_emb = (const float*)d_in[6];
    const float* Wq        = (const float*)d_in[7];
    const float* Wk        = (const float*)d_in[8];
    const float* Wv        = (const float*)d_in[9];
    const float* aW1       = (const float*)d_in[10];
    const float* ab1       = (const float*)d_in[11];
    const float* aW2       = (const float*)d_in[12];
    const float* ab2       = (const float*)d_in[13];
    const float* kW1       = (const float*)d_in[14];
    const float* kb1       = (const float*)d_in[15];
    const float* kW2       = (const float*)d_in[16];
    const float* kb2       = (const float*)d_in[17];
    const float* vW1       = (const float*)d_in[18];
    const float* vb1       = (const float*)d_in[19];
    const float* vW2       = (const float*)d_in[20];
    const float* vb2       = (const float*)d_in[21];
    const float* gk        = (const float*)d_in[22];
    const float* gv        = (const float*)d_in[23];
    const float* log_temp  = (const float*)d_in[24];

    float* out   = (float*)d_out;
    float* memb  = out;                        // mem, later overwritten by mem_k
    float* query = out + (size_t)NTOK * NC;    // query, later overwritten by mem_v

    // workspace layout (floats)
    float* w     = (float*)d_ws;
    float* sk    = w;                  // 327680
    float* sv    = sk    + 327680;     // 327680
    float* ksT   = sv    + 327680;     // 327680
    float* kcT   = ksT   + 327680;     // 10485760
    float* vc    = kcT   + 10485760;   // 10485760
    float* alph  = vc    + 10485760;   // 21760
    float* bias2 = alph  + 21760;      // 40960
    float* bufA  = bias2 + 40960;      // 2621440
    float* bufB  = bufA  + 2621440;    // 2621440
    float* bufC  = bufB  + 2621440;    // 2621440
    if (ws_size < (size_t)29881600 * 4) return;
    if (out_size < 2 * NTOK * NC + 2) return;

    const dim3 blk256(256);

    // projections (batch-independent)
    gemm128<<<dim3(170, 8), blk256, 0, stream>>>(x, Wq, query, NTOK, NC, NC, nullptr, nullptr);
    gemm128<<<dim3(3, 8),   blk256, 0, stream>>>(sm, Wk, sk, 320, NC, NC, nullptr, nullptr);
    gemm128<<<dim3(3, 8),   blk256, 0, stream>>>(sm, Wv, sv, 320, NC, NC, nullptr, nullptr);
    gemm128<<<dim3(20, 8),  blk256, 0, stream>>>(cat_B, Wk, bufA, 2560, NC, NC, nullptr, nullptr);
    gemm128<<<dim3(20, 8),  blk256, 0, stream>>>(cat_B, Wv, bufB, 2560, NC, NC, nullptr, nullptr);

    // transposed key layouts
    transpose32<<<dim3(32, 10), blk256, 0, stream>>>(sk,   ksT,  320,  1024);
    transpose32<<<dim3(32, 80), blk256, 0, stream>>>(bufA, bufC, 2560, 1024);

    // per-batch low-rank expanded K/V memories
    build_kcT<<<dim3(NB, 1024), dim3(320), 0, stream>>>(ksT, bufC, cat_A, cat_ids, kcT);
    build_vc<<<dim3(NB, 320), blk256, 0, stream>>>(sv, bufB, cat_A, cat_ids, vc);

    // alpha gate
    bias2_kernel<<<dim3(NB * 10), dim3(128), 0, stream>>>(cat_emb, scale_emb, aW1, ab1, cat_ids, bias2);
    alpha_kernel<<<dim3(NB * NCHUNK), dim3(128), 0, stream>>>(query, aW1, aW2, ab2, bias2, cat_ids, alph);

    // fused dual attention -> mem (in d_out)
    attn_kernel2<<<dim3(NTILE * NB), blk256, 0, stream>>>(query, ksT, kcT, sv, vc, alph, log_temp, memb);

    // final low-rank projections
    gemm128<<<dim3(170, 1), blk256, 0, stream>>>(memb, kW1, bufA, NTOK, 64, NC, kb1, nullptr);
    gemm128<<<dim3(170, 1), blk256, 0, stream>>>(memb, vW1, bufB, NTOK, 64, NC, vb1, nullptr);
    gemm128<<<dim3(170, 8), blk256, 0, stream>>>(bufA, kW2, memb, NTOK, NC, 64, kb2, gk);
    gemm128<<<dim3(170, 8), blk256, 0, stream>>>(bufB, vW2, query, NTOK, NC, 64, vb2, gv);

    tail_zero<<<1, 64, 0, stream>>>(out + (size_t)2 * NTOK * NC);
}

// Round 4
// 2199.232 us; speedup vs baseline: 1.9894x; 1.4553x over previous
//
#include <hip/hip_runtime.h>
#include <math.h>

// Problem constants
#define NB 32          // batch
#define NC 1024        // channels
#define LTOT 680       // total tokens per batch
#define NTOK (NB*NC > 0 ? NB*LTOT : 0) // 21760
#define NKMAX 320      // 10 scales * 32 slots
#define NCHUNK 90      // 8-token chunks across all scales (alpha kernel)
#define NTILE 27       // 32-token tiles across all scales (attn kernel)

typedef unsigned short u16;
typedef __bf16 bf16x8 __attribute__((ext_vector_type(8)));
typedef float floatx4 __attribute__((ext_vector_type(4)));

__device__ __forceinline__ u16 f2bf(float f)
{
    union { float f; unsigned u; } v; v.f = f;
    unsigned u = v.u;
    u += 0x7FFFu + ((u >> 16) & 1u);   // RNE
    return (u16)(u >> 16);
}

// ---------------------------------------------------------------------------
// chunk -> (scale, l0, nq) lookup for alpha kernel (8-token chunks).
// ---------------------------------------------------------------------------
__device__ __forceinline__ void chunk_info(int chunk, int* pi, int* pl0, int* pnq)
{
    const int cb[10] = {0,1,2,4,6,10,15,23,36,58};
    const int sb[10] = {0,1,5,14,30,55,91,155,255,424};
    const int se[10] = {1,5,14,30,55,91,155,255,424,680};
    int ii = 0;
#pragma unroll
    for (int k = 1; k < 10; ++k) if (chunk >= cb[k]) ii = k;
    int l0 = sb[ii] + (chunk - cb[ii]) * 8;
    int nq = se[ii] - l0; if (nq > 8) nq = 8;
    *pi = ii; *pl0 = l0; *pnq = nq;
}

// 32-token attention tiles, heavy-first for tail balance.
__device__ __constant__ int d_tscale[NTILE] =
    {9,9,9,9,9,9,9,9, 8,8,8,8,8,8, 7,7,7,7, 6,6, 5,5, 4,3,2,1,0};
__device__ __constant__ int d_tl0[NTILE] =
    {424,456,488,520,552,584,616,648, 255,287,319,351,383,415,
     155,187,219,251, 91,123, 55,87, 30,14,5,1,0};
__device__ __constant__ int d_tnt[NTILE] =
    {32,32,32,32,32,32,32,32, 32,32,32,32,32,9, 32,32,32,4, 32,32, 32,4, 25,16,9,4,1};

// ---------------------------------------------------------------------------
// bf16 MFMA GEMM (m97-style): C[MxN] fp32 = A[MxK] @ B, with B given as
// BT[NxK] bf16 row-major. 128x128 tile, BK=64, 256 threads = 4 waves in a
// 2x2 wave grid; each wave computes 4x4 frags of 16x16 (64x64 quadrant).
// LDS holds A/B tiles in FRAGMENT ORDER: [tile*2+kh][lane][8 bf16] so every
// ds_read/ds_write is lane-linear b128 (conflict-free).
// A-frag: lane holds A[m=16t+(lane&15)][k=kh*32+(lane>>4)*8+j]
// C/D:    col=lane&15, row=(lane>>4)*4+reg   (m89-verified)
// AFP32=1: A is fp32, cast to bf16 inline during staging.
// M,N arbitrary (clamped loads, guarded stores); K multiple of 64.
// ---------------------------------------------------------------------------
template<int AFP32>
__global__ __launch_bounds__(256) void gemm_mfma(
    const void* __restrict__ Av, const u16* __restrict__ BT,
    float* __restrict__ C, int M, int N, int K,
    const float* __restrict__ bias, const float* __restrict__ scale_logit)
{
    __shared__ __align__(16) u16 As[16 * 64 * 8];   // 16KB
    __shared__ __align__(16) u16 Bs[16 * 64 * 8];   // 16KB

    const int tid  = threadIdx.x;
    const int m0   = blockIdx.x << 7;
    const int n0   = blockIdx.y << 7;
    const int wave = tid >> 6;
    const int lane = tid & 63;
    const int mh   = wave & 1;
    const int nh   = wave >> 1;

    floatx4 acc[4][4];
#pragma unroll
    for (int i = 0; i < 4; ++i)
#pragma unroll
        for (int j = 0; j < 4; ++j) acc[i][j] = (floatx4){0.f, 0.f, 0.f, 0.f};

    for (int k0 = 0; k0 < K; k0 += 64) {
        __syncthreads();
        // ---- stage A tile (128 rows x 64 k) into frag order ----
        if (AFP32) {
            const float* A = (const float*)Av;
#pragma unroll
            for (int p = 0; p < 8; ++p) {
                int q   = tid + (p << 8);          // 2048 chunks of 4 floats
                int row = q >> 4;
                int fq  = q & 15;                  // 4-float chunk within row
                int gr  = m0 + row; if (gr > M - 1) gr = M - 1;
                const float4 a4 = *(const float4*)(A + (size_t)gr * K + k0 + (fq << 2));
                int kh = fq >> 3, quad = (fq >> 1) & 3, jh = fq & 1;
                u16* d = &As[((((row >> 4) << 1) | kh) * 64 + (quad << 4) + (row & 15)) * 8 + (jh << 2)];
                d[0] = f2bf(a4.x); d[1] = f2bf(a4.y); d[2] = f2bf(a4.z); d[3] = f2bf(a4.w);
            }
        } else {
            const u16* A = (const u16*)Av;
#pragma unroll
            for (int p = 0; p < 4; ++p) {
                int q   = tid + (p << 8);          // 1024 chunks of 8 bf16
                int row = q >> 3;
                int cq  = q & 7;
                int gr  = m0 + row; if (gr > M - 1) gr = M - 1;
                *(uint4*)&As[((((row >> 4) << 1) | (cq >> 2)) * 64 + ((cq & 3) << 4) + (row & 15)) * 8]
                    = *(const uint4*)(A + (size_t)gr * K + k0 + (cq << 3));
            }
        }
        // ---- stage B tile (BT rows = output cols) ----
#pragma unroll
        for (int p = 0; p < 4; ++p) {
            int q   = tid + (p << 8);
            int row = q >> 3;
            int cq  = q & 7;
            int gn  = n0 + row; if (gn > N - 1) gn = N - 1;
            *(uint4*)&Bs[((((row >> 4) << 1) | (cq >> 2)) * 64 + ((cq & 3) << 4) + (row & 15)) * 8]
                = *(const uint4*)(BT + (size_t)gn * K + k0 + (cq << 3));
        }
        __syncthreads();
        // ---- MFMA over the two K-halves ----
#pragma unroll
        for (int kh = 0; kh < 2; ++kh) {
            bf16x8 a[4], b[4];
#pragma unroll
            for (int i = 0; i < 4; ++i)
                a[i] = *(const bf16x8*)&As[(((((mh << 2) + i) << 1) | kh) * 64 + lane) * 8];
#pragma unroll
            for (int j = 0; j < 4; ++j)
                b[j] = *(const bf16x8*)&Bs[(((((nh << 2) + j) << 1) | kh) * 64 + lane) * 8];
#pragma unroll
            for (int i = 0; i < 4; ++i)
#pragma unroll
                for (int j = 0; j < 4; ++j)
                    acc[i][j] = __builtin_amdgcn_mfma_f32_16x16x32_bf16(a[i], b[j], acc[i][j], 0, 0, 0);
        }
    }

    float scale = 1.f;
    if (scale_logit) scale = 1.f / (1.f + __expf(-scale_logit[0]));
    const int col = lane & 15, rquad = lane >> 4;
#pragma unroll
    for (int i = 0; i < 4; ++i) {
#pragma unroll
        for (int j = 0; j < 4; ++j) {
#pragma unroll
            for (int r = 0; r < 4; ++r) {
                int gr = m0 + (mh << 6) + (i << 4) + (rquad << 2) + r;
                int gc = n0 + (nh << 6) + (j << 4) + col;
                if (gr < M && gc < N) {
                    float bb = bias ? bias[gc] : 0.f;
                    C[(size_t)gr * N + gc] = scale * (acc[i][j][r] + bb);
                }
            }
        }
    }
}

// ---------------------------------------------------------------------------
// fp32 elementwise -> bf16 (n4 = element count / 4)
// ---------------------------------------------------------------------------
__global__ __launch_bounds__(256) void castbf(
    const float* __restrict__ in, u16* __restrict__ out, int n4)
{
    int i = blockIdx.x * 256 + threadIdx.x;
    const int stride = gridDim.x * 256;
    for (; i < n4; i += stride) {
        const float4 v = ((const float4*)in)[i];
        uint2 o;
        o.x = (unsigned)f2bf(v.x) | ((unsigned)f2bf(v.y) << 16);
        o.y = (unsigned)f2bf(v.z) | ((unsigned)f2bf(v.w) << 16);
        ((uint2*)out)[i] = o;
    }
}

// ---------------------------------------------------------------------------
// transpose + cast: out[Cc][R] bf16 = in[R][Cc]^T.
// grid MUST be (ceil(Cc/32), ceil(R/32)) — guarded for safety.
// ---------------------------------------------------------------------------
__global__ __launch_bounds__(256) void tcast(
    const float* __restrict__ in, u16* __restrict__ out, int R, int Cc)
{
    __shared__ float t[32][33];
    const int bx = blockIdx.x * 32;   // Cc
    const int by = blockIdx.y * 32;   // R
    const int x = threadIdx.x & 31;
    const int y0 = threadIdx.x >> 5;
#pragma unroll
    for (int yy = y0; yy < 32; yy += 8)
        t[yy][x] = (by + yy < R && bx + x < Cc)
                 ? in[(size_t)(by + yy) * Cc + bx + x] : 0.f;
    __syncthreads();
#pragma unroll
    for (int yy = y0; yy < 32; yy += 8)
        if (bx + yy < Cc && by + x < R)
            out[(size_t)(bx + yy) * R + by + x] = f2bf(t[x][yy]);
}

// ---------------------------------------------------------------------------
// 32x32 fp32 transpose, same grid convention, guarded.
// ---------------------------------------------------------------------------
__global__ __launch_bounds__(256) void transpose32(
    const float* __restrict__ in, float* __restrict__ out, int R, int Cc)
{
    __shared__ float t[32][33];
    const int bx = blockIdx.x * 32;
    const int by = blockIdx.y * 32;
    const int x = threadIdx.x & 31;
    const int y0 = threadIdx.x >> 5;
#pragma unroll
    for (int yy = y0; yy < 32; yy += 8)
        t[yy][x] = (by + yy < R && bx + x < Cc)
                 ? in[(size_t)(by + yy) * Cc + bx + x] : 0.f;
    __syncthreads();
#pragma unroll
    for (int yy = y0; yy < 32; yy += 8)
        if (bx + yy < Cc && by + x < R)
            out[(size_t)(bx + yy) * R + by + x] = t[x][yy];
}

// ---------------------------------------------------------------------------
// kcT[b][c][j] = ksT[c][j] + sum_r a[b,v,r] * catBKT[c][(v*8+r)*32+slot]
// ---------------------------------------------------------------------------
__global__ __launch_bounds__(320) void build_kcT(
    const float* __restrict__ ksT, const float* __restrict__ catBKT,
    const float* __restrict__ cat_A, const int* __restrict__ cat_ids,
    float* __restrict__ kcT)
{
    __shared__ float aS[80];
    const int b = blockIdx.x;
    const int c = blockIdx.y;
    const int tid = threadIdx.x;
    if (tid < 80) {
        int cid = cat_ids[b]; if (cid < 0) cid = 0;
        aS[tid] = cat_A[cid * 80 + tid];
    }
    __syncthreads();
    const int j = tid;
    const int v = j >> 5, slot = j & 31;
    float acc = ksT[(size_t)c * 320 + j];
    const float* row = catBKT + (size_t)c * 2560;
#pragma unroll
    for (int r = 0; r < 8; ++r)
        acc = fmaf(aS[v * 8 + r], row[(v * 8 + r) * 32 + slot], acc);
    kcT[((size_t)b * 1024 + c) * 320 + j] = acc;
}

// ---------------------------------------------------------------------------
// vc[b][j][c] = shared_v[j][c] + sum_r a[b,v,r] * cat_BV[(v,r,slot)][c]
// ---------------------------------------------------------------------------
__global__ __launch_bounds__(256) void build_vc(
    const float* __restrict__ sv, const float* __restrict__ catBV,
    const float* __restrict__ cat_A, const int* __restrict__ cat_ids,
    float* __restrict__ vc)
{
    const int b = blockIdx.x;
    const int jrow = blockIdx.y;
    const int v = jrow >> 5, slot = jrow & 31;
    int cid = cat_ids[b]; if (cid < 0) cid = 0;
    float a[8];
#pragma unroll
    for (int r = 0; r < 8; ++r) a[r] = cat_A[(cid * 10 + v) * 8 + r];
    const int c = threadIdx.x << 2;
    float4 acc = *(const float4*)(sv + (size_t)jrow * 1024 + c);
#pragma unroll
    for (int r = 0; r < 8; ++r) {
        const float4 bv = *(const float4*)(catBV + (size_t)((v * 8 + r) * 32 + slot) * 1024 + c);
        acc.x = fmaf(a[r], bv.x, acc.x);
        acc.y = fmaf(a[r], bv.y, acc.y);
        acc.z = fmaf(a[r], bv.z, acc.z);
        acc.w = fmaf(a[r], bv.w, acc.w);
    }
    *(float4*)(vc + ((size_t)b * 320 + jrow) * 1024 + c) = acc;
}

// ---------------------------------------------------------------------------
// bias2[b][i][j] = ce[b]@aW1[1024:2048,j] + scale_emb[i]@aW1[2048:3072,j] + ab1[j]
// ---------------------------------------------------------------------------
__global__ __launch_bounds__(128) void bias2_kernel(
    const float* __restrict__ cat_emb, const float* __restrict__ scale_emb,
    const float* __restrict__ aW1, const float* __restrict__ ab1,
    const int* __restrict__ cat_ids, float* __restrict__ bias2)
{
    const int b = blockIdx.x / 10;
    const int i = blockIdx.x - b * 10;
    const int j = threadIdx.x;
    int cid = cat_ids[b]; if (cid < 0) cid = 0;
    const float* ce = cat_emb + (size_t)cid * 1024;
    const float* se = scale_emb + (size_t)i * 1024;
    float acc = ab1[j];
    for (int c = 0; c < 1024; ++c) {
        acc = fmaf(ce[c], aW1[(size_t)(1024 + c) * 128 + j], acc);
        acc = fmaf(se[c], aW1[(size_t)(2048 + c) * 128 + j], acc);
    }
    bias2[(b * 10 + i) * 128 + j] = acc;
}

// ---------------------------------------------------------------------------
// alpha[b][l] = valid ? sigmoid( gelu(q@aW1_top + bias2[b,i]) @ aW2 + ab2 ) : 0
// ---------------------------------------------------------------------------
__global__ __launch_bounds__(128) void alpha_kernel(
    const float* __restrict__ query, const float* __restrict__ aW1,
    const float* __restrict__ aW2, const float* __restrict__ ab2,
    const float* __restrict__ bias2, const int* __restrict__ cat_ids,
    float* __restrict__ alpha)
{
    __shared__ float qs[8][1024];
    __shared__ float red[8][128];
    const int tid = threadIdx.x;
    const int blk = blockIdx.x;
    const int b = blk / NCHUNK;
    const int chunk = blk - b * NCHUNK;
    int isc, l0, nq;
    chunk_info(chunk, &isc, &l0, &nq);
    const size_t qbase = ((size_t)b * LTOT + l0) * 1024;

    for (int idx = tid; idx < 8 * 256; idx += 128) {
        int t = idx >> 8;
        int c4 = (idx & 255) << 2;
        float4 v = make_float4(0.f, 0.f, 0.f, 0.f);
        if (t < nq) v = *(const float4*)(query + qbase + (size_t)t * 1024 + c4);
        *(float4*)&qs[t][c4] = v;
    }
    __syncthreads();
    const int j = tid;
    float acc[8];
#pragma unroll
    for (int t = 0; t < 8; ++t) acc[t] = 0.f;
    for (int c = 0; c < 1024; ++c) {
        float w = aW1[(size_t)c * 128 + j];
#pragma unroll
        for (int t = 0; t < 8; ++t) acc[t] = fmaf(qs[t][c], w, acc[t]);
    }
    const float b2 = bias2[(b * 10 + isc) * 128 + j];
    const float w2 = aW2[j];
#pragma unroll
    for (int t = 0; t < 8; ++t) {
        float h = acc[t] + b2;
        h = 0.5f * h * (1.0f + erff(h * 0.70710678118654752f));
        red[t][j] = h * w2;
    }
    __syncthreads();
    if (tid < 8) {
        float s = 0.f;
        for (int jj = 0; jj < 128; ++jj) s += red[tid][jj];
        if (tid < nq) {
            float al = 0.f;
            if (cat_ids[b] >= 0) al = 1.f / (1.f + expf(-(s + ab2[0])));
            alpha[b * LTOT + l0 + tid] = al;
        }
    }
}

// ---------------------------------------------------------------------------
// Fused dual attention: 32-token tiles, per-type sequential passes.
// pS stride 324 (== 4 mod 32) kills the 8-way phase-2 bank conflicts.
// ---------------------------------------------------------------------------
__global__ __launch_bounds__(256) void attn_kernel2(
    const float* __restrict__ query, const float* __restrict__ ksT,
    const float* __restrict__ kcT, const float* __restrict__ vs,
    const float* __restrict__ vc, const float* __restrict__ alpha,
    const float* __restrict__ log_temp, float* __restrict__ memo)
{
    __shared__ float kS[8][320];   // [c8][j] one type at a time
    __shared__ float Qs[8][36];    // [c8][tok]
    __shared__ float pS[32][324];  // [tok][j], stride%32==4 -> conflict-free

    const int tid = threadIdx.x;
    const int tile = blockIdx.x >> 5;
    const int b    = blockIdx.x & 31;

    const int isc  = d_tscale[tile];
    const int l0   = d_tl0[tile];
    const int ntok = d_tnt[tile];
    const int NK   = (isc + 1) << 5;
    const int NK4  = NK >> 2;
    const int NKu  = (NK + 63) >> 6;

    const int lane = tid & 63;
    const int tg   = tid >> 6;
    const int tg8  = tg << 3;

    const size_t qbase = ((size_t)b * LTOT + l0) * 1024;

    float temp = __expf(log_temp[0]);
    temp = fminf(fmaxf(temp, 0.05f), 1.0f);
    const float Ksc = 0.03125f / temp;

    const int sr = tid >> 5;
    const int sc = tid & 31;

    for (int type = 0; type < 2; ++type) {
        const float* kT = type ? (kcT + (size_t)b * 1024 * 320) : ksT;
        const float* V  = type ? (vc  + (size_t)b * 320 * 1024) : vs;

        // ---------- phase 1: logits ----------
        float acc[8][5];
#pragma unroll
        for (int t = 0; t < 8; ++t)
#pragma unroll
            for (int u = 0; u < 5; ++u) acc[t][u] = 0.f;

        for (int cc = 0; cc < 1024; cc += 8) {
            __syncthreads();
            {
                const float4* src4 = (const float4*)(kT + (size_t)(cc + sr) * 320);
                float4* dst4 = (float4*)&kS[sr][0];
                for (int k = sc; k < NK4; k += 32) dst4[k] = src4[k];
            }
            {
                int c8 = tid >> 5, t = tid & 31;
                Qs[c8][t] = (t < ntok) ? query[qbase + (size_t)t * 1024 + cc + c8] : 0.f;
            }
            __syncthreads();
#pragma unroll
            for (int c8 = 0; c8 < 8; ++c8) {
                float qv[8];
                *(float4*)&qv[0] = *(float4*)&Qs[c8][tg8];
                *(float4*)&qv[4] = *(float4*)&Qs[c8][tg8 + 4];
#pragma unroll
                for (int u = 0; u < 5; ++u) {
                    if (u >= NKu) break;
                    int j = lane + (u << 6);
                    float kv = (j < NK) ? kS[c8][j] : 0.f;
#pragma unroll
                    for (int t = 0; t < 8; ++t)
                        acc[t][u] = fmaf(qv[t], kv, acc[t][u]);
                }
            }
        }
#pragma unroll
        for (int u = 0; u < 5; ++u) {
            if (u >= NKu) break;
            int j = lane + (u << 6);
            if (j < NK) {
#pragma unroll
                for (int t = 0; t < 8; ++t) pS[tg8 + t][j] = acc[t][u];
            }
        }
        __syncthreads();

        // ---------- phase 2: softmax + alpha weighting ----------
        {
            const int tok = tid >> 3;
            const int sj  = tid & 7;
            float mx = -1e30f;
            for (int j = sj; j < NK; j += 8) mx = fmaxf(mx, pS[tok][j]);
#pragma unroll
            for (int k = 4; k >= 1; k >>= 1) mx = fmaxf(mx, __shfl_xor(mx, k, 8));
            float sum = 0.f;
            for (int j = sj; j < NK; j += 8) {
                float e = __expf((pS[tok][j] - mx) * Ksc);
                pS[tok][j] = e;
                sum += e;
            }
#pragma unroll
            for (int k = 4; k >= 1; k >>= 1) sum += __shfl_xor(sum, k, 8);
            float al = (tok < ntok) ? alpha[b * LTOT + l0 + tok] : 0.f;
            float wgt = type ? al : (1.f - al);
            float inv = wgt / sum;
            for (int j = sj; j < NK; j += 8) pS[tok][j] *= inv;
        }
        __syncthreads();

        // ---------- phase 3: O += P @ V ----------
        {
            const int nvalid = ntok - tg8;
#pragma unroll 1
            for (int slab = 0; slab < 4; ++slab) {
                float4 a3[8];
#pragma unroll
                for (int t = 0; t < 8; ++t) a3[t] = make_float4(0.f, 0.f, 0.f, 0.f);
                const float* Vb = V + (slab << 8) + (lane << 2);
#pragma unroll 4
                for (int j = 0; j < NK; ++j) {
                    const float4 v4 = *(const float4*)(Vb + (size_t)j * 1024);
                    float p[8];
#pragma unroll
                    for (int t = 0; t < 8; ++t) p[t] = pS[tg8 + t][j];
#pragma unroll
                    for (int t = 0; t < 8; ++t) {
                        a3[t].x = fmaf(p[t], v4.x, a3[t].x);
                        a3[t].y = fmaf(p[t], v4.y, a3[t].y);
                        a3[t].z = fmaf(p[t], v4.z, a3[t].z);
                        a3[t].w = fmaf(p[t], v4.w, a3[t].w);
                    }
                }
#pragma unroll
                for (int t = 0; t < 8; ++t) {
                    if (t < nvalid) {
                        float* op = memo + qbase + (size_t)(tg8 + t) * 1024
                                    + (slab << 8) + (lane << 2);
                        if (type == 0) {
                            *(float4*)op = a3[t];
                        } else {
                            float4 o = *(const float4*)op;
                            o.x += a3[t].x; o.y += a3[t].y;
                            o.z += a3[t].z; o.w += a3[t].w;
                            *(float4*)op = o;
                        }
                    }
                }
            }
        }
        __syncthreads();
    }
}

__global__ void tail_zero(float* p)
{
    if (threadIdx.x < 2) p[threadIdx.x] = 0.f;
}

// ---------------------------------------------------------------------------
extern "C" void kernel_launch(void* const* d_in, const int* in_sizes, int n_in,
                              void* d_out, int out_size, void* d_ws, size_t ws_size,
                              hipStream_t stream)
{
    (void)in_sizes; (void)n_in;
    const float* x         = (const float*)d_in[0];
    const int*   cat_ids   = (const int*)  d_in[1];
    const float* sm        = (const float*)d_in[2];
    const float* cat_A     = (const float*)d_in[3];
    const float* cat_B     = (const float*)d_in[4];
    const float* cat_emb   = (const float*)d_in[5];
    const float* scale_emb = (const float*)d_in[6];
    const float* Wq        = (const float*)d_in[7];
    const float* Wk        = (const float*)d_in[8];
    const float* Wv        = (const float*)d_in[9];
    const float* aW1       = (const float*)d_in[10];
    const float* ab1       = (const float*)d_in[11];
    const float* aW2       = (const float*)d_in[12];
    const float* ab2       = (const float*)d_in[13];
    const float* kW1       = (const float*)d_in[14];
    const float* kb1       = (const float*)d_in[15];
    const float* kW2       = (const float*)d_in[16];
    const float* kb2       = (const float*)d_in[17];
    const float* vW1       = (const float*)d_in[18];
    const float* vb1       = (const float*)d_in[19];
    const float* vW2       = (const float*)d_in[20];
    const float* vb2       = (const float*)d_in[21];
    const float* gk        = (const float*)d_in[22];
    const float* gv        = (const float*)d_in[23];
    const float* log_temp  = (const float*)d_in[24];

    float* out   = (float*)d_out;
    float* memb  = out;                          // mem, later overwritten by mem_k
    float* query = out + (size_t)21760 * 1024;   // query, later overwritten by mem_v

    // workspace layout (floats)
    float* w     = (float*)d_ws;
    float* sk    = w;                  // 327680
    float* sv    = sk    + 327680;     // 327680
    float* ksT   = sv    + 327680;     // 327680
    float* kcT   = ksT   + 327680;     // 10485760
    float* vc    = kcT   + 10485760;   // 10485760
    float* alph  = vc    + 10485760;   // 21760
    float* bias2 = alph  + 21760;      // 40960
    float* bufA  = bias2 + 40960;      // 2621440
    float* bufB  = bufA  + 2621440;    // 2621440
    float* bufC  = bufB  + 2621440;    // 2621440
    if (ws_size < (size_t)29881600 * 4) return;
    if (out_size < 2 * 21760 * 1024 + 2) return;

    // --- overlays (lifetime-disjoint with their hosts) ---
    u16* x_bf  = (u16*)kcT;                    // dead before build_kcT writes
    u16* WqT   = (u16*)bufC;                   // dead before catBKT transpose
    u16* WkT   = WqT + 1048576;
    u16* WvT   = WkT + 1048576;
    u16* kW1T  = (u16*)sk;                     // written after sk is consumed
    u16* vW1T  = kW1T + 65536;
    u16* kW2T  = vW1T + 65536;
    u16* vW2T  = kW2T + 65536;

    const dim3 blk256(256);

    // 0. casts / weight transposes (tcast grid = (Cc/32, R/32))
    castbf<<<dim3(2048), blk256, 0, stream>>>(x, x_bf, 21760 * 1024 / 4);
    tcast<<<dim3(32, 32), blk256, 0, stream>>>(Wq, WqT, 1024, 1024);
    tcast<<<dim3(32, 32), blk256, 0, stream>>>(Wk, WkT, 1024, 1024);
    tcast<<<dim3(32, 32), blk256, 0, stream>>>(Wv, WvT, 1024, 1024);

    // 1. projections (MFMA)
    gemm_mfma<0><<<dim3(170, 8), blk256, 0, stream>>>(x_bf, WqT, query, 21760, 1024, 1024, nullptr, nullptr);
    gemm_mfma<1><<<dim3(3, 8),   blk256, 0, stream>>>(sm,   WkT, sk,    320,  1024, 1024, nullptr, nullptr);
    gemm_mfma<1><<<dim3(3, 8),   blk256, 0, stream>>>(sm,   WvT, sv,    320,  1024, 1024, nullptr, nullptr);
    gemm_mfma<1><<<dim3(20, 8),  blk256, 0, stream>>>(cat_B, WkT, bufA, 2560, 1024, 1024, nullptr, nullptr);
    gemm_mfma<1><<<dim3(20, 8),  blk256, 0, stream>>>(cat_B, WvT, bufB, 2560, 1024, 1024, nullptr, nullptr);

    // 2. transposed fp32 key layouts for attention
    transpose32<<<dim3(32, 10), blk256, 0, stream>>>(sk,   ksT,  320,  1024);
    // small weight transposes AFTER sk is consumed (they overlay sk)
    // kW1/vW1: [R=1024][Cc=64] -> grid (2, 32); kW2/vW2: [R=64][Cc=1024] -> grid (32, 2)
    tcast<<<dim3(2, 32), blk256, 0, stream>>>(kW1, kW1T, 1024, 64);
    tcast<<<dim3(2, 32), blk256, 0, stream>>>(vW1, vW1T, 1024, 64);
    tcast<<<dim3(32, 2), blk256, 0, stream>>>(kW2, kW2T, 64, 1024);
    tcast<<<dim3(32, 2), blk256, 0, stream>>>(vW2, vW2T, 64, 1024);
    // catBK^T (clobbers WqT/WkT/WvT — dead now)
    transpose32<<<dim3(32, 80), blk256, 0, stream>>>(bufA, bufC, 2560, 1024);

    // 3. per-batch low-rank expanded K/V (kcT write clobbers x_bf — dead now)
    build_kcT<<<dim3(NB, 1024), dim3(320), 0, stream>>>(ksT, bufC, cat_A, cat_ids, kcT);
    build_vc<<<dim3(NB, 320), blk256, 0, stream>>>(sv, bufB, cat_A, cat_ids, vc);

    // 4. alpha gate
    bias2_kernel<<<dim3(NB * 10), dim3(128), 0, stream>>>(cat_emb, scale_emb, aW1, ab1, cat_ids, bias2);
    alpha_kernel<<<dim3(NB * NCHUNK), dim3(128), 0, stream>>>(query, aW1, aW2, ab2, bias2, cat_ids, alph);

    // 5. fused dual attention -> mem (in d_out)
    attn_kernel2<<<dim3(NTILE * NB), blk256, 0, stream>>>(query, ksT, kcT, sv, vc, alph, log_temp, memb);

    // 6. final low-rank projections (MFMA, inline-cast fp32 A)
    gemm_mfma<1><<<dim3(170, 1), blk256, 0, stream>>>(memb, kW1T, bufA, 21760, 64, 1024, kb1, nullptr);
    gemm_mfma<1><<<dim3(170, 1), blk256, 0, stream>>>(memb, vW1T, bufB, 21760, 64, 1024, vb1, nullptr);
    gemm_mfma<1><<<dim3(170, 8), blk256, 0, stream>>>(bufA, kW2T, memb, 21760, 1024, 64, kb2, gk);
    gemm_mfma<1><<<dim3(170, 8), blk256, 0, stream>>>(bufB, vW2T, query, 21760, 1024, 64, vb2, gv);

    tail_zero<<<1, 64, 0, stream>>>(out + (size_t)2 * 21760 * 1024);
}